// Round 1
// baseline (1341.423 us; speedup 1.0000x reference)
//
#include <hip/hip_runtime.h>
#include <math.h>
#include <stdint.h>

// Problem constants
constexpr int B   = 8;
constexpr int DIM = 128;
constexpr int S   = 1024;
constexpr int CF  = 512;
constexpr int K   = 16384;
constexpr float INV_TAU = 5.0f;    // 1/0.2
constexpr float EPSF    = 1e-12f;

// Output layout (flat, in return order): output_g [B,1+K], target_g [B],
// output_d [B,1+K,S], target_d [B,S]
constexpr int64_t OG_OFF = 0;
constexpr int64_t TG_OFF = (int64_t)B * (K + 1);                 // 131080
constexpr int64_t OD_OFF = TG_OFF + B;                           // 131088
constexpr int64_t TD_OFF = OD_OFF + (int64_t)B * (K + 1) * S;    // 134357008

// ---------------------------------------------------------------------------
// Zero the int32 target outputs (bit pattern 0 is valid as both f32 and i32)
__global__ void zero_targets_kernel(float* out) {
    int t = blockIdx.x * 256 + threadIdx.x;
    if (t < B) out[TG_OFF + t] = 0.0f;
    if (t < B * S) out[TD_OFF + t] = 0.0f;
}

// ---------------------------------------------------------------------------
// Normalize g_q, g_k (axis=1, D=128); emit g_qn, g_kn and pos_g logits.
// One block per b, 128 threads (2 waves).
__global__ void g_norm_kernel(const float* __restrict__ g_q,
                              const float* __restrict__ g_k,
                              float* __restrict__ g_qn,
                              float* __restrict__ g_kn,
                              float* __restrict__ out) {
    int b = blockIdx.x;
    int d = threadIdx.x;  // 0..127
    float q = g_q[b * DIM + d];
    float k = g_k[b * DIM + d];
    float sq = q * q, sk = k * k;
#pragma unroll
    for (int off = 32; off > 0; off >>= 1) {
        sq += __shfl_down(sq, off, 64);
        sk += __shfl_down(sk, off, 64);
    }
    __shared__ float red[4];
    int w = d >> 6;
    if ((d & 63) == 0) { red[w] = sq; red[2 + w] = sk; }
    __syncthreads();
    float invq = 1.0f / fmaxf(sqrtf(red[0] + red[1]), EPSF);
    float invk = 1.0f / fmaxf(sqrtf(red[2] + red[3]), EPSF);
    float qn = q * invq, kn = k * invk;
    g_qn[b * DIM + d] = qn;
    g_kn[b * DIM + d] = kn;
    float p = qn * kn;
#pragma unroll
    for (int off = 32; off > 0; off >>= 1) p += __shfl_down(p, off, 64);
    __shared__ float red2[2];
    if ((d & 63) == 0) red2[w] = p;
    __syncthreads();
    if (d == 0) out[OG_OFF + (int64_t)b * (K + 1)] = (red2[0] + red2[1]) * INV_TAU;
}

// ---------------------------------------------------------------------------
// neg_g: out[b, 1+k] = (g_qn[b,:] . queue_g[:,k]) / TAU.  64 blocks x 256 thr,
// one thread per k, all 8 batches accumulated per thread (queue read once).
__global__ void neg_g_kernel(const float* __restrict__ g_qn,
                             const float* __restrict__ queue_g,
                             float* __restrict__ out) {
    __shared__ float gq[B * DIM];
    int t = threadIdx.x;
    for (int i = t; i < B * DIM; i += 256) gq[i] = g_qn[i];
    __syncthreads();
    int k = blockIdx.x * 256 + t;
    float acc[B] = {0, 0, 0, 0, 0, 0, 0, 0};
    for (int d = 0; d < DIM; ++d) {
        float v = queue_g[(int64_t)d * K + k];
#pragma unroll
        for (int b = 0; b < B; ++b) acc[b] = fmaf(gq[b * DIM + d], v, acc[b]);
    }
#pragma unroll
    for (int b = 0; b < B; ++b)
        out[OG_OFF + (int64_t)b * (K + 1) + 1 + k] = acc[b] * INV_TAU;
}

// ---------------------------------------------------------------------------
// Inverse L2 norms along the channel axis of x[B,ROWS,S] -> rn[B,S].
// Block = 256 threads = 64 s-lanes x 4 row-groups.
template <int ROWS>
__global__ void invnorm_kernel(const float* __restrict__ x, float* __restrict__ rn) {
    int b = blockIdx.y;
    int s = blockIdx.x * 64 + (threadIdx.x & 63);
    int g = threadIdx.x >> 6;
    const float* base = x + (int64_t)b * ROWS * S + s;
    float acc = 0.0f;
    for (int r = g; r < ROWS; r += 4) {
        float v = base[(int64_t)r * S];
        acc = fmaf(v, v, acc);
    }
    __shared__ float red[256];
    red[threadIdx.x] = acc;
    __syncthreads();
    if (g == 0) {
        int sl = threadIdx.x;
        float tot = red[sl] + red[64 + sl] + red[128 + sl] + red[192 + sl];
        rn[b * S + s] = 1.0f / fmaxf(sqrtf(tot), EPSF);
    }
}

// ---------------------------------------------------------------------------
// cosine[b,i,j] = sum_c fk[b,c,i]*fq[b,c,j] * rn_fk[b,i]*rn_fq[b,j];
// partial argmax over i within this block's i-chunk of 256.
// grid (j_tiles=16, i_chunks=4, B); block 256 = (tx,ty) 16x16; 4x4 reg tile.
constexpr int CC = 32;
__global__ void cos_argmax_kernel(const float* __restrict__ f_k,
                                  const float* __restrict__ f_q,
                                  const float* __restrict__ rn_fk,
                                  const float* __restrict__ rn_fq,
                                  float* __restrict__ pmax,
                                  int* __restrict__ pidx) {
    int jt = blockIdx.x, ic = blockIdx.y, b = blockIdx.z;
    int j0 = jt * 64;
    int tx = threadIdx.x & 15, ty = threadIdx.x >> 4;
    __shared__ __align__(16) float sk[CC][68];
    __shared__ __align__(16) float sq[CC][68];
    const float* fkb = f_k + (int64_t)b * CF * S;
    const float* fqb = f_q + (int64_t)b * CF * S;

    float bestv[4];
    int besti[4];
#pragma unroll
    for (int jj = 0; jj < 4; ++jj) { bestv[jj] = -INFINITY; besti[jj] = 0; }
    float rq[4];
#pragma unroll
    for (int jj = 0; jj < 4; ++jj) rq[jj] = rn_fq[b * S + j0 + ty * 4 + jj];

    for (int it = 0; it < 4; ++it) {
        int i_base = ic * 256 + it * 64;
        float acc[4][4] = {};
        for (int c0 = 0; c0 < CF; c0 += CC) {
            for (int e = threadIdx.x; e < CC * 64; e += 256) {
                int r = e >> 6, col = e & 63;
                sk[r][col] = fkb[(int64_t)(c0 + r) * S + i_base + col];
                sq[r][col] = fqb[(int64_t)(c0 + r) * S + j0 + col];
            }
            __syncthreads();
#pragma unroll
            for (int r = 0; r < CC; ++r) {
                float4 av4 = *(const float4*)&sk[r][tx * 4];
                float4 bv4 = *(const float4*)&sq[r][ty * 4];
                float a_[4] = {av4.x, av4.y, av4.z, av4.w};
                float b_[4] = {bv4.x, bv4.y, bv4.z, bv4.w};
#pragma unroll
                for (int ii = 0; ii < 4; ++ii)
#pragma unroll
                    for (int jj = 0; jj < 4; ++jj)
                        acc[ii][jj] = fmaf(a_[ii], b_[jj], acc[ii][jj]);
            }
            __syncthreads();
        }
        float rk[4];
#pragma unroll
        for (int ii = 0; ii < 4; ++ii) rk[ii] = rn_fk[b * S + i_base + tx * 4 + ii];
        // fold (ascending i keeps numpy first-max semantics with strict >)
#pragma unroll
        for (int jj = 0; jj < 4; ++jj)
#pragma unroll
            for (int ii = 0; ii < 4; ++ii) {
                float v = acc[ii][jj] * rk[ii] * rq[jj];
                if (v > bestv[jj]) { bestv[jj] = v; besti[jj] = i_base + tx * 4 + ii; }
            }
    }
    // reduce across the 16 tx lanes (contiguous within a wave)
#pragma unroll
    for (int jj = 0; jj < 4; ++jj) {
        float v = bestv[jj];
        int idx = besti[jj];
#pragma unroll
        for (int off = 8; off > 0; off >>= 1) {
            float ov = __shfl_down(v, off, 16);
            int oi = __shfl_down(idx, off, 16);
            if (ov > v || (ov == v && oi < idx)) { v = ov; idx = oi; }
        }
        if (tx == 0) {
            int j = j0 + ty * 4 + jj;
            pmax[(int64_t)(ic * B + b) * S + j] = v;
            pidx[(int64_t)(ic * B + b) * S + j] = idx;
        }
    }
}

// Merge the 4 i-chunk partials -> match_idx[b,s]
__global__ void argmax_merge_kernel(const float* __restrict__ pmax,
                                    const int* __restrict__ pidx,
                                    int* __restrict__ match) {
    int t = blockIdx.x * 256 + threadIdx.x;
    if (t >= B * S) return;
    int b = t / S, s = t % S;
    float bv = -INFINITY;
    int bi = 0;
    for (int ic = 0; ic < 4; ++ic) {
        float v = pmax[(int64_t)(ic * B + b) * S + s];
        int i = pidx[(int64_t)(ic * B + b) * S + s];
        if (v > bv || (v == bv && i < bi)) { bv = v; bi = i; }
    }
    match[t] = bi;
}

// ---------------------------------------------------------------------------
// d_qg[b,d,z] = d_q[b,d,match[b,z]] * rn_dq[b,match[b,z]]   (normalized gather)
__global__ void gather_kernel(const float* __restrict__ d_q,
                              const float* __restrict__ rn_dq,
                              const int* __restrict__ match,
                              float* __restrict__ d_qg) {
    int64_t t = (int64_t)blockIdx.x * 256 + threadIdx.x;  // B*DIM*S
    int z = (int)(t & (S - 1));
    int64_t bd = t >> 10;
    int b = (int)(bd >> 7);
    int m = match[b * S + z];
    d_qg[t] = d_q[(bd << 10) + m] * rn_dq[b * S + m];
}

// ---------------------------------------------------------------------------
// pos_d: out[b,0,z] = (d_kn[b,:,z] . d_qg[b,:,z]) / TAU  (d_k norm fused)
__global__ void pos_d_kernel(const float* __restrict__ d_k,
                             const float* __restrict__ d_qg,
                             float* __restrict__ out) {
    int t = blockIdx.x * 256 + threadIdx.x;  // B*S
    if (t >= B * S) return;
    int b = t / S, z = t % S;
    float dot = 0.0f, nk = 0.0f;
    for (int d = 0; d < DIM; ++d) {
        float kv = d_k[((int64_t)b * DIM + d) * S + z];
        float qv = d_qg[((int64_t)b * DIM + d) * S + z];
        dot = fmaf(kv, qv, dot);
        nk = fmaf(kv, kv, nk);
    }
    float pos = dot / fmaxf(sqrtf(nk), EPSF);
    out[OD_OFF + (int64_t)b * (K + 1) * S + z] = pos * INV_TAU;
}

// ---------------------------------------------------------------------------
// neg_d: out[b,1+q,z] = (queue_d[:,q] . d_qg[b,:,z]) / TAU
// grid (q_tiles=256, z_tiles=16, B); block 256; 64x64 tile, 4x4 per thread.
__global__ void neg_d_kernel(const float* __restrict__ queue_d,
                             const float* __restrict__ d_qg,
                             float* __restrict__ out) {
    int q0 = blockIdx.x * 64, z0 = blockIdx.y * 64, b = blockIdx.z;
    int tx = threadIdx.x & 15, ty = threadIdx.x >> 4;
    __shared__ __align__(16) float sa[16][68];  // queue_d tile [d][q]
    __shared__ __align__(16) float sb[16][68];  // d_qg tile    [d][z]
    float acc[4][4] = {};
    const float* qg = d_qg + (int64_t)b * DIM * S;
    for (int d0 = 0; d0 < DIM; d0 += 16) {
        for (int e = threadIdx.x; e < 16 * 64; e += 256) {
            int r = e >> 6, col = e & 63;
            sa[r][col] = queue_d[(int64_t)(d0 + r) * K + q0 + col];
            sb[r][col] = qg[(int64_t)(d0 + r) * S + z0 + col];
        }
        __syncthreads();
#pragma unroll
        for (int r = 0; r < 16; ++r) {
            float4 av4 = *(const float4*)&sa[r][ty * 4];
            float4 bv4 = *(const float4*)&sb[r][tx * 4];
            float a_[4] = {av4.x, av4.y, av4.z, av4.w};
            float b_[4] = {bv4.x, bv4.y, bv4.z, bv4.w};
#pragma unroll
            for (int qq = 0; qq < 4; ++qq)
#pragma unroll
                for (int zz = 0; zz < 4; ++zz)
                    acc[qq][zz] = fmaf(a_[qq], b_[zz], acc[qq][zz]);
        }
        __syncthreads();
    }
#pragma unroll
    for (int qq = 0; qq < 4; ++qq) {
        int64_t q = q0 + ty * 4 + qq;
        float4 w;
        w.x = acc[qq][0] * INV_TAU;
        w.y = acc[qq][1] * INV_TAU;
        w.z = acc[qq][2] * INV_TAU;
        w.w = acc[qq][3] * INV_TAU;
        *(float4*)&out[OD_OFF + ((int64_t)b * (K + 1) + 1 + q) * S + z0 + tx * 4] = w;
    }
}

// ---------------------------------------------------------------------------
extern "C" void kernel_launch(void* const* d_in, const int* in_sizes, int n_in,
                              void* d_out, int out_size, void* d_ws, size_t ws_size,
                              hipStream_t stream) {
    const float* g_q     = (const float*)d_in[0];
    const float* g_k     = (const float*)d_in[1];
    const float* d_q     = (const float*)d_in[2];
    const float* d_k     = (const float*)d_in[3];
    const float* feat_q  = (const float*)d_in[4];
    const float* feat_k  = (const float*)d_in[5];
    const float* queue_g = (const float*)d_in[6];
    const float* queue_d = (const float*)d_in[7];
    float* out = (float*)d_out;

    // Workspace carve (floats), ~4.4 MB total
    float* ws    = (float*)d_ws;
    float* g_qn  = ws;               // 1024
    float* g_kn  = g_qn + 1024;      // 1024
    float* rn_fq = g_kn + 1024;      // 8192
    float* rn_fk = rn_fq + B * S;    // 8192
    float* rn_dq = rn_fk + B * S;    // 8192
    float* pmax  = rn_dq + B * S;    // 4*8192
    int*   pidx  = (int*)(pmax + 4 * B * S);  // 4*8192
    int*   match = pidx + 4 * B * S;          // 8192
    float* d_qg  = (float*)(match + B * S);   // B*DIM*S

    zero_targets_kernel<<<(B * S + 255) / 256, 256, 0, stream>>>(out);
    g_norm_kernel<<<B, DIM, 0, stream>>>(g_q, g_k, g_qn, g_kn, out);
    neg_g_kernel<<<K / 256, 256, 0, stream>>>(g_qn, queue_g, out);
    invnorm_kernel<CF><<<dim3(S / 64, B), 256, 0, stream>>>(feat_q, rn_fq);
    invnorm_kernel<CF><<<dim3(S / 64, B), 256, 0, stream>>>(feat_k, rn_fk);
    invnorm_kernel<DIM><<<dim3(S / 64, B), 256, 0, stream>>>(d_q, rn_dq);
    cos_argmax_kernel<<<dim3(S / 64, 4, B), 256, 0, stream>>>(feat_k, feat_q, rn_fk, rn_fq, pmax, pidx);
    argmax_merge_kernel<<<(B * S + 255) / 256, 256, 0, stream>>>(pmax, pidx, match);
    gather_kernel<<<(B * DIM * S) / 256, 256, 0, stream>>>(d_q, rn_dq, match, d_qg);
    pos_d_kernel<<<(B * S + 255) / 256, 256, 0, stream>>>(d_k, d_qg, out);
    neg_d_kernel<<<dim3(K / 64, S / 64, B), 256, 0, stream>>>(queue_d, d_qg, out);
}